// Round 11
// baseline (147.856 us; speedup 1.0000x reference)
//
#include <hip/hip_runtime.h>

#define HID 1024
#define RANK 16
#define NSEG 64
#define NCHUNK 16          // grid = 64*16 = 1024 blocks, 512-token slices
#define NXCD 8

__global__ __launch_bounds__(256, 2) void lora_v11(
    const float* __restrict__ x,      // [N, H]
    const int*   __restrict__ seg,    // [N]
    const float* __restrict__ A,      // [S, H, R]
    const float* __restrict__ B,      // [S, R, H]
    const float* __restrict__ bias,   // [S, H]
    float*       __restrict__ out,    // [N, H]
    int N)
{
    // XCD-bijective swizzle (1024 = 8*128): each XCD owns 8 segments.
    const int work = (blockIdx.x & (NXCD - 1)) * ((NSEG * NCHUNK) / NXCD)
                   + (blockIdx.x >> 3);
    const int s = work >> 4;                  // NCHUNK == 16
    const int c = work & (NCHUNK - 1);
    const int tid  = threadIdx.x;
    const int lane = tid & 63;
    const int w    = tid >> 6;

    __shared__ int   list[512];
    __shared__ int   cnt;
    __shared__ float red[4][16][68];          // per-wave transpose-reduce pad
    __shared__ float inter_lds[2][4][RANK];   // double-buffered

    if (tid == 0) cnt = 0;

    // ---- hoist B, A, bias to REGISTERS once per block; loads fill during scan ----
    const float4* B4 = (const float4*)(B + (size_t)s * RANK * HID);
    float4 br[4][4];                          // [rr][k]: B row w*4+rr, h-chunk k
    #pragma unroll
    for (int rr = 0; rr < 4; ++rr)
        #pragma unroll
        for (int k = 0; k < 4; ++k)
            br[rr][k] = B4[(size_t)(w * 4 + rr) * (HID / 4) + k * 64 + lane];

    const float4* A4 = (const float4*)(A + (size_t)s * HID * RANK);
    float4 av[4][4];                          // [jh][q]: A row tid*4+jh, r-quad q
    #pragma unroll
    for (int jh = 0; jh < 4; ++jh)
        #pragma unroll
        for (int q = 0; q < 4; ++q)
            av[jh][q] = A4[(size_t)(tid * 4 + jh) * (RANK / 4) + q];
    const float4 bia = ((const float4*)(bias + (size_t)s * HID))[tid];

    __syncthreads();                          // cnt=0 visible

    // ---- scan 512-token slice ----
    const int chunkN = (N + NCHUNK - 1) / NCHUNK;
    const int i0 = c * chunkN;
    const int i1 = min(N, i0 + chunkN);
    for (int i = i0 + tid; i < i1; i += 256)
        if (seg[i] == s) list[atomicAdd(&cnt, 1)] = i;
    __syncthreads();
    const int m = cnt;
    if (m == 0) return;

    const int v = lane & 15;
    const int q = lane >> 4;

    // ---- group-0 tokens + x loads ----
    int n[4];
    #pragma unroll
    for (int j = 0; j < 4; ++j) n[j] = list[min(j, m - 1)];
    float4 xv[4][4];
    #pragma unroll
    for (int j = 0; j < 4; ++j) {
        const float4* xr = (const float4*)(x + (size_t)n[j] * HID);
        #pragma unroll
        for (int k = 0; k < 4; ++k) xv[j][k] = xr[k * 64 + lane];
    }

    for (int t = 0; t < m; t += 4) {
        const int nt = min(4, m - t);
        int ns[4];                            // this group's store targets
        #pragma unroll
        for (int j = 0; j < 4; ++j) ns[j] = n[j];

        // ---- phase 1 FMA: consume xv (B from registers) ----
        float acc[4][4];                      // [rr][j]
        #pragma unroll
        for (int rr = 0; rr < 4; ++rr)
            #pragma unroll
            for (int j = 0; j < 4; ++j) acc[rr][j] = 0.f;
        #pragma unroll
        for (int k = 0; k < 4; ++k)
            #pragma unroll
            for (int j = 0; j < 4; ++j) {
                const float4 xj = xv[j][k];
                #pragma unroll
                for (int rr = 0; rr < 4; ++rr)
                    acc[rr][j] += br[rr][k].x * xj.x + br[rr][k].y * xj.y
                                + br[rr][k].z * xj.z + br[rr][k].w * xj.w;
            }

        // ---- prefetch NEXT group's x into xv (in flight under reduce+phase2) ----
        if (t + 4 < m) {
            #pragma unroll
            for (int j = 0; j < 4; ++j) n[j] = list[min(t + 4 + j, m - 1)];
            #pragma unroll
            for (int j = 0; j < 4; ++j) {
                const float4* xr = (const float4*)(x + (size_t)n[j] * HID);
                #pragma unroll
                for (int k = 0; k < 4; ++k) xv[j][k] = xr[k * 64 + lane];
            }
        }

        // ---- wave-local transpose-reduce ----
        #pragma unroll
        for (int rr = 0; rr < 4; ++rr)
            #pragma unroll
            for (int j = 0; j < 4; ++j)
                red[w][rr * 4 + j][lane] = acc[rr][j];
        const float4* rp = (const float4*)&red[w][v][q * 16];
        float4 r0 = rp[0], r1 = rp[1], r2 = rp[2], r3 = rp[3];
        float sum = ((r0.x + r0.y) + (r0.z + r0.w))
                  + ((r1.x + r1.y) + (r1.z + r1.w))
                  + ((r2.x + r2.y) + (r2.z + r2.w))
                  + ((r3.x + r3.y) + (r3.z + r3.w));
        sum += __shfl_xor(sum, 16, 64);
        sum += __shfl_xor(sum, 32, 64);
        const int buf = (t >> 2) & 1;
        if (lane < 16) inter_lds[buf][v & 3][w * 4 + (v >> 2)] = sum;
        __syncthreads();                       // one barrier per group

        // ---- phase 2: A and bias from registers, inter broadcast from LDS ----
        #pragma unroll
        for (int j = 0; j < 4; ++j) {
            const float4* I4 = (const float4*)inter_lds[buf][j];
            float4 iv[4];
            #pragma unroll
            for (int qq = 0; qq < 4; ++qq) iv[qq] = I4[qq];
            float4 o = bia;
            float* op = (float*)&o;
            #pragma unroll
            for (int jh = 0; jh < 4; ++jh) {
                float a = 0.f;
                #pragma unroll
                for (int qq = 0; qq < 4; ++qq)
                    a += av[jh][qq].x * iv[qq].x + av[jh][qq].y * iv[qq].y
                       + av[jh][qq].z * iv[qq].z + av[jh][qq].w * iv[qq].w;
                op[jh] += a;
            }
            if (j < nt)
                ((float4*)(out + (size_t)ns[j] * HID))[tid] = o;
        }
    }
}

extern "C" void kernel_launch(void* const* d_in, const int* in_sizes, int n_in,
                              void* d_out, int out_size, void* d_ws, size_t ws_size,
                              hipStream_t stream) {
    const float* x    = (const float*)d_in[0];
    const int*   seg  = (const int*)d_in[1];
    const float* A    = (const float*)d_in[2];
    const float* B    = (const float*)d_in[3];
    const float* bias = (const float*)d_in[4];
    float* out = (float*)d_out;

    const int n_tokens = in_sizes[1];

    lora_v11<<<NSEG * NCHUNK, 256, 0, stream>>>(x, seg, A, B, bias, out, n_tokens);
}